// Round 14
// baseline (178.098 us; speedup 1.0000x reference)
//
#include <hip/hip_runtime.h>
#include <hip/hip_bf16.h>

#define N_NODES 10000
#define N_EDGES 320000
#define D 256

typedef __attribute__((ext_vector_type(8))) _Float16 f16x8;
typedef __attribute__((ext_vector_type(4))) _Float16 f16x4;
typedef __attribute__((ext_vector_type(4))) float f32x4;

__device__ __forceinline__ void async_copy16(const void* g, void* l) {
  __builtin_amdgcn_global_load_lds(
      (const __attribute__((address_space(1))) unsigned int*)g,
      (__attribute__((address_space(3))) unsigned int*)l, 16, 0, 0);
}

// stage ROWS x 32 f16 k-chunk into Bs[ROWS*32] with XOR quad swizzle; WAVES waves cooperate
template<int ROWS, int WAVES>
__device__ __forceinline__ void stage_tile(const _Float16* __restrict__ Wb, int k0, int K,
                                           _Float16* Bs, int wave, int lane) {
  const int sr = lane >> 2, ss = lane & 3;
#pragma unroll
  for (int grp = wave; grp < ROWS / 16; grp += WAVES) {
    int r = grp * 16 + sr;
    int gq = ss ^ ((r >> 1) & 3);
    async_copy16(Wb + (size_t)r * K + k0 + gq * 8, Bs + grp * 512);
  }
}
__device__ __forceinline__ f16x8 read_B(const _Float16* Bs, int r, int quad) {
  return *(const f16x8*)(Bs + r * 32 + (quad ^ ((r >> 1) & 3)) * 8);
}

// direct B-fragment load: W row-major [N x K], fragment = 8 f16 at (row, kc*32 + quad*8)
__device__ __forceinline__ f16x8 load_B(const _Float16* __restrict__ W, int row, int K,
                                        int kc, int quad) {
  return *(const f16x8*)(W + (size_t)row * K + kc * 32 + quad * 8);
}

__device__ __forceinline__ float fast_sigmoid(float x) {
  return __builtin_amdgcn_rcpf(1.f + __expf(-x));
}
__device__ __forceinline__ float fast_tanh(float x) {
  float ax = fabsf(x);
  float e = __expf(-2.f * ax);
  float t = (1.f - e) * __builtin_amdgcn_rcpf(1.f + e);
  return copysignf(t, x);
}

// ---------- K0: cnt zeroing + all weight casts (absorbs memset) ----------
__global__ __launch_bounds__(512) void prep_cast(
    int* __restrict__ cnt,
    const float* __restrict__ W_rel, const float* __restrict__ W_ih,
    const float* __restrict__ b_ih, const float* __restrict__ b_hh,
    const float* __restrict__ W1, const float* __restrict__ W2,
    const float* __restrict__ W3,
    _Float16* __restrict__ W_relh, _Float16* __restrict__ Wg,
    float* __restrict__ bg,
    _Float16* __restrict__ W1h, _Float16* __restrict__ W2h,
    _Float16* __restrict__ W3h) {
  int i = blockIdx.x * 512 + threadIdx.x;
  if (i < 10240) { if (i < N_NODES) cnt[i] = 0; return; }
  i -= 10240;
  if (i < 131072) { W_relh[i] = (_Float16)W_rel[i]; return; }
  i -= 131072;
  if (i < 196608) {
    // packed row p = 48t + 16*phase + u -> W_ih row (16t+u) + {0,512,768}[phase] (f-gate dropped: c0=0)
    int p = i >> 8, k = i & 255;
    int t = p / 48, rem = p - t * 48;
    int phase = rem >> 4, u = rem & 15;
    int orig = t * 16 + u + (phase == 1 ? 512 : (phase == 2 ? 768 : 0));
    Wg[i] = (_Float16)W_ih[orig * 256 + k]; return;
  }
  i -= 196608;
  if (i < 32768) { W1h[i] = (_Float16)W1[i]; return; }
  i -= 32768;
  if (i < 16384) { W2h[i] = (_Float16)W2[i]; return; }
  i -= 16384;
  if (i < 32768) { W3h[i] = (_Float16)W3[i]; return; }
  i -= 32768;
  if (i < 768) {
    int t = i / 48, rem = i - t * 48;
    int phase = rem >> 4, u = rem & 15;
    int orig = t * 16 + u + (phase == 1 ? 512 : (phase == 2 ? 768 : 0));
    bg[i] = b_ih[orig] + b_hh[orig];
  }
}

// ---------- K1: fused edge NN (M=64, 8 waves, DOUBLE-BUFFERED staged W) + bucket fill ----------
// stage(kc+1) issued before compute(kc): L2 latency hides under MFMAs; 1 barrier per kc.
__global__ __launch_bounds__(512) void edge_fill(
    const float* __restrict__ feat, const _Float16* __restrict__ W_relh,
    const float* __restrict__ b_rel, _Float16* __restrict__ Mh,
    const int* __restrict__ dst, const int* __restrict__ src,
    const int* __restrict__ rel,
    int* __restrict__ cnt, unsigned int* __restrict__ rowoff)
{
  __shared__ _Float16 Hs[64 * 266];                // 34,048 B
  __shared__ alignas(16) _Float16 Bs[2][256 * 32]; // 32,768 B (double-buffered)
  const int b = blockIdx.x;
  if (b >= 314) {
    // bucket-fill role: runs concurrently with the edge GEMM blocks
    int i = (b - 314) * 512 + threadIdx.x;   // 625*512 == N_EDGES exactly
    int v = dst[i];
    int pos = atomicAdd(&cnt[v], 1);
    if (pos < 128)   // capacity guard; P(deg>128) ~ 1e-40 for E/N=32
      rowoff[(v << 7) + pos] = (unsigned int)((rel[i] * N_NODES + src[i]) * D);
    return;
  }
  const int t = threadIdx.x;
  const int wave = t >> 6, lane = t & 63;
  const int quad = lane >> 4, lrow = lane & 15;
  const int z = (b >= 157) ? 1 : 0;
  const int m0 = (b - z * 157) * 64;
  const _Float16* Wb = W_relh + z * 65536;
  const float* bb = b_rel + z * 256;
  const int wm = (wave >> 2) * 32;
  const int wn = (wave & 3) * 64;

  int ar0 = m0 + wm + lrow;      if (ar0 > N_NODES - 1) ar0 = N_NODES - 1;
  int ar1 = m0 + wm + 16 + lrow; if (ar1 > N_NODES - 1) ar1 = N_NODES - 1;
  const float* fr0 = feat + (size_t)ar0 * 256;
  const float* fr1 = feat + (size_t)ar1 * 256;

  f32x4 acc[2][4];
#pragma unroll
  for (int i = 0; i < 2; ++i)
#pragma unroll
    for (int j = 0; j < 4; ++j) acc[i][j] = (f32x4)0.0f;

  // ---- layer 1: dbuf pipeline ----
  stage_tile<256, 8>(Wb, 0, 256, Bs[0], wave, lane);
  __syncthreads();   // drain stage(0)
#pragma unroll
  for (int kc = 0; kc < 8; ++kc) {
    if (kc < 7)   // issue next chunk into the other buffer; hides under MFMAs below
      stage_tile<256, 8>(Wb, (kc + 1) * 32, 256, Bs[(kc + 1) & 1], wave, lane);
    float4 u0 = *(const float4*)(fr0 + kc * 32 + quad * 8);
    float4 u1 = *(const float4*)(fr0 + kc * 32 + quad * 8 + 4);
    float4 v0 = *(const float4*)(fr1 + kc * 32 + quad * 8);
    float4 v1 = *(const float4*)(fr1 + kc * 32 + quad * 8 + 4);
    f16x8 af0, af1;
    af0[0] = (_Float16)u0.x; af0[1] = (_Float16)u0.y; af0[2] = (_Float16)u0.z; af0[3] = (_Float16)u0.w;
    af0[4] = (_Float16)u1.x; af0[5] = (_Float16)u1.y; af0[6] = (_Float16)u1.z; af0[7] = (_Float16)u1.w;
    af1[0] = (_Float16)v0.x; af1[1] = (_Float16)v0.y; af1[2] = (_Float16)v0.z; af1[3] = (_Float16)v0.w;
    af1[4] = (_Float16)v1.x; af1[5] = (_Float16)v1.y; af1[6] = (_Float16)v1.z; af1[7] = (_Float16)v1.w;
    const _Float16* Bcur = Bs[kc & 1];
#pragma unroll
    for (int j = 0; j < 4; ++j) {
      f16x8 bf = read_B(Bcur, wn + j * 16 + lrow, quad);
      acc[0][j] = __builtin_amdgcn_mfma_f32_16x16x32_f16(af0, bf, acc[0][j], 0, 0, 0);
      acc[1][j] = __builtin_amdgcn_mfma_f32_16x16x32_f16(af1, bf, acc[1][j], 0, 0, 0);
    }
    __syncthreads();   // drains stage(kc+1); protects Bs[kc&1] before overwrite at kc+2
  }
#pragma unroll
  for (int i = 0; i < 2; ++i) {
    int rb = wm + i * 16 + quad * 4;
#pragma unroll
    for (int j = 0; j < 4; ++j) {
      int col = wn + j * 16 + lrow;
      float bv = bb[col];
#pragma unroll
      for (int reg = 0; reg < 4; ++reg) {
        Hs[(rb + reg) * 266 + col] = (_Float16)fmaxf(acc[i][j][reg] + bv, 0.f);
        acc[i][j][reg] = 0.f;
      }
    }
  }
  // layer-2 prologue stage issued before the Hs-handoff barrier (one barrier serves both)
  stage_tile<256, 8>(Wb, 0, 256, Bs[0], wave, lane);
  __syncthreads();

  // ---- layer 2: A from Hs, dbuf pipeline (tied weight) ----
#pragma unroll
  for (int kc = 0; kc < 8; ++kc) {
    if (kc < 7)
      stage_tile<256, 8>(Wb, (kc + 1) * 32, 256, Bs[(kc + 1) & 1], wave, lane);
    f16x8 af0 = *(const f16x8*)(Hs + (wm + lrow) * 266 + kc * 32 + quad * 8);
    f16x8 af1 = *(const f16x8*)(Hs + (wm + 16 + lrow) * 266 + kc * 32 + quad * 8);
    const _Float16* Bcur = Bs[kc & 1];
#pragma unroll
    for (int j = 0; j < 4; ++j) {
      f16x8 bf = read_B(Bcur, wn + j * 16 + lrow, quad);
      acc[0][j] = __builtin_amdgcn_mfma_f32_16x16x32_f16(af0, bf, acc[0][j], 0, 0, 0);
      acc[1][j] = __builtin_amdgcn_mfma_f32_16x16x32_f16(af1, bf, acc[1][j], 0, 0, 0);
    }
    __syncthreads();
  }
  _Float16* Mo = Mh + (size_t)z * (N_NODES * D);
#pragma unroll
  for (int i = 0; i < 2; ++i) {
    int rb = m0 + wm + i * 16 + quad * 4;
#pragma unroll
    for (int j = 0; j < 4; ++j) {
      int col = wn + j * 16 + lrow;
      float bv = bb[col];
#pragma unroll
      for (int reg = 0; reg < 4; ++reg) {
        int gm = rb + reg;
        if (gm < N_NODES)
          Mo[(size_t)gm * D + col] = (_Float16)fmaxf(acc[i][j][reg] + bv, 0.f);
      }
    }
  }
}

// ---------- K2: aggregation v3 (R13-proven): offsets staged to LDS, f16x8 loads, unroll-2 ----------
__global__ __launch_bounds__(256) void agg_kernel(const int* __restrict__ cnt,
                                                  const unsigned int* __restrict__ rowoff,
                                                  const _Float16* __restrict__ Mh,
                                                  _Float16* __restrict__ aggh) {
  __shared__ unsigned int soff[128];
  __shared__ float part[4][256];
  const int node = blockIdx.x;
  const int tid = threadIdx.x;
  const int wave = tid >> 6, lane = tid & 63;
  const int half = lane >> 5, li = lane & 31;
  const int base = node << 7;
  if (tid < 128) soff[tid] = rowoff[base + tid];
  int deg = cnt[node]; if (deg > 128) deg = 128;
  __syncthreads();

  float a0 = 0.f, a1 = 0.f, a2 = 0.f, a3 = 0.f, a4 = 0.f, a5 = 0.f, a6 = 0.f, a7 = 0.f;
  // lane handles channels li*8..li*8+7 of rows j = wave*2 + half (+8k); offsets from LDS
  int j = wave * 2 + half;
  for (; j + 8 < deg; j += 16) {   // unroll-2: two row loads in flight
    unsigned int offA = soff[j];
    unsigned int offB = soff[j + 8];
    f16x8 vA = *(const f16x8*)(Mh + (size_t)offA + li * 8);
    f16x8 vB = *(const f16x8*)(Mh + (size_t)offB + li * 8);
    a0 += (float)vA[0] + (float)vB[0]; a1 += (float)vA[1] + (float)vB[1];
    a2 += (float)vA[2] + (float)vB[2]; a3 += (float)vA[3] + (float)vB[3];
    a4 += (float)vA[4] + (float)vB[4]; a5 += (float)vA[5] + (float)vB[5];
    a6 += (float)vA[6] + (float)vB[6]; a7 += (float)vA[7] + (float)vB[7];
  }
  for (; j < deg; j += 8) {
    unsigned int off = soff[j];
    f16x8 v = *(const f16x8*)(Mh + (size_t)off + li * 8);
    a0 += (float)v[0]; a1 += (float)v[1]; a2 += (float)v[2]; a3 += (float)v[3];
    a4 += (float)v[4]; a5 += (float)v[5]; a6 += (float)v[6]; a7 += (float)v[7];
  }
  // combine the two 32-lane halves — all lanes reconverged here, shfl is safe
  a0 += __shfl_xor(a0, 32); a1 += __shfl_xor(a1, 32);
  a2 += __shfl_xor(a2, 32); a3 += __shfl_xor(a3, 32);
  a4 += __shfl_xor(a4, 32); a5 += __shfl_xor(a5, 32);
  a6 += __shfl_xor(a6, 32); a7 += __shfl_xor(a7, 32);
  if (lane < 32) {   // lanes 0..31 store the wave partial (32..63 duplicate)
    *(float4*)&part[wave][li * 8]     = make_float4(a0, a1, a2, a3);
    *(float4*)&part[wave][li * 8 + 4] = make_float4(a4, a5, a6, a7);
  }
  __syncthreads();
  if (wave == 0) {
    float4 p0 = *(const float4*)&part[0][lane * 4];
    float4 p1 = *(const float4*)&part[1][lane * 4];
    float4 p2 = *(const float4*)&part[2][lane * 4];
    float4 p3 = *(const float4*)&part[3][lane * 4];
    f16x4 o;
    o[0] = (_Float16)(p0.x + p1.x + p2.x + p3.x);
    o[1] = (_Float16)(p0.y + p1.y + p2.y + p3.y);
    o[2] = (_Float16)(p0.z + p1.z + p2.z + p3.z);
    o[3] = (_Float16)(p0.w + p1.w + p2.w + p3.w);
    *(f16x4*)(aggh + (size_t)node * D + lane * 4) = o;
  }
}

// ---------- K3: tail (R8-proven), M=64/block, ping-pong prefetch, direct B-loads ----------
__global__ __launch_bounds__(512) void tail(
    const _Float16* __restrict__ aggh,
    const _Float16* __restrict__ Wg, const float* __restrict__ bg,
    const _Float16* __restrict__ W1h, const float* __restrict__ b1,
    const _Float16* __restrict__ W2h, const float* __restrict__ b2,
    const _Float16* __restrict__ W3h, const float* __restrict__ b3,
    float* __restrict__ out)
{
  __shared__ _Float16 Hn[64 * 266];    // 34,048 B
  __shared__ _Float16 Xs[64 * 138];    // 17,664 B
  __shared__ _Float16 X2s[64 * 138];   // 17,664 B
  const int t = threadIdx.x;
  const int wave = t >> 6, lane = t & 63;
  const int quad = lane >> 4, lrow = lane & 15;
  const int r0 = blockIdx.x * 64;   // 157 * 64 = 10048 >= N_NODES (guarded)

  int ar[4];
#pragma unroll
  for (int m = 0; m < 4; ++m) {
    int a = r0 + m * 16 + lrow;
    ar[m] = (a > N_NODES - 1) ? (N_NODES - 1) : a;
  }

  // ---- Phase B: gates + LSTM -> Hn (8 waves x 6 gate-tiles x 4 m-subtiles) ----
  {
    f32x4 acc[4][6];
#pragma unroll
    for (int m = 0; m < 4; ++m)
#pragma unroll
      for (int j = 0; j < 6; ++j) acc[m][j] = (f32x4)0.0f;

    f16x8 afp[2][4], bfp[2][6];
#pragma unroll
    for (int m = 0; m < 4; ++m)
      afp[0][m] = *(const f16x8*)(aggh + (size_t)ar[m] * 256 + quad * 8);
#pragma unroll
    for (int j = 0; j < 6; ++j)
      bfp[0][j] = load_B(Wg, (wave * 6 + j) * 16 + lrow, 256, 0, quad);

#pragma unroll
    for (int kc = 0; kc < 8; ++kc) {
      const int cur = kc & 1, nxt = cur ^ 1;
      if (kc < 7) {   // prefetch kc+1 while MFMAs below run on kc
#pragma unroll
        for (int m = 0; m < 4; ++m)
          afp[nxt][m] = *(const f16x8*)(aggh + (size_t)ar[m] * 256 + (kc + 1) * 32 + quad * 8);
#pragma unroll
        for (int j = 0; j < 6; ++j)
          bfp[nxt][j] = load_B(Wg, (wave * 6 + j) * 16 + lrow, 256, kc + 1, quad);
      }
#pragma unroll
      for (int j = 0; j < 6; ++j)
#pragma unroll
        for (int m = 0; m < 4; ++m)
          acc[m][j] = __builtin_amdgcn_mfma_f32_16x16x32_f16(afp[cur][m], bfp[cur][j], acc[m][j], 0, 0, 0);
    }
#pragma unroll
    for (int m = 0; m < 4; ++m) {
#pragma unroll
      for (int p = 0; p < 2; ++p) {
        float bvi = bg[(wave * 6 + 3 * p + 0) * 16 + lrow];
        float bvg = bg[(wave * 6 + 3 * p + 1) * 16 + lrow];
        float bvo = bg[(wave * 6 + 3 * p + 2) * 16 + lrow];
        int dcol = (wave * 2 + p) * 16 + lrow;
#pragma unroll
        for (int reg = 0; reg < 4; ++reg) {
          float vi = acc[m][3 * p + 0][reg] + bvi;
          float vg = acc[m][3 * p + 1][reg] + bvg;
          float vo = acc[m][3 * p + 2][reg] + bvo;
          float c = fast_sigmoid(vi) * fast_tanh(vg);
          Hn[(m * 16 + quad * 4 + reg) * 266 + dcol] = (_Float16)(fast_sigmoid(vo) * fast_tanh(c));
        }
      }
    }
  }
  __syncthreads();

  // ---- Phase C: x1 (1 N-tile/wave, 4 m; A from LDS, B prefetched) ----
  {
    f32x4 acc[4];
#pragma unroll
    for (int m = 0; m < 4; ++m) acc[m] = (f32x4)0.0f;
    f16x8 bfp[2];
    bfp[0] = load_B(W1h, wave * 16 + lrow, 256, 0, quad);
#pragma unroll
    for (int kc = 0; kc < 8; ++kc) {
      const int cur = kc & 1, nxt = cur ^ 1;
      if (kc < 7) bfp[nxt] = load_B(W1h, wave * 16 + lrow, 256, kc + 1, quad);
#pragma unroll
      for (int m = 0; m < 4; ++m) {
        f16x8 a = *(const f16x8*)(Hn + (m * 16 + lrow) * 266 + kc * 32 + quad * 8);
        acc[m] = __builtin_amdgcn_mfma_f32_16x16x32_f16(a, bfp[cur], acc[m], 0, 0, 0);
      }
    }
    int col = wave * 16 + lrow;
    float bv = b1[col];
#pragma unroll
    for (int m = 0; m < 4; ++m)
#pragma unroll
      for (int reg = 0; reg < 4; ++reg)
        Xs[(m * 16 + quad * 4 + reg) * 138 + col] = (_Float16)fmaxf(acc[m][reg] + bv, 0.f);
  }
  __syncthreads();

  // ---- Phase D: x2 (1 N-tile/wave, 4 m) ----
  {
    f32x4 acc[4];
#pragma unroll
    for (int m = 0; m < 4; ++m) acc[m] = (f32x4)0.0f;
    f16x8 bfp[2];
    bfp[0] = load_B(W2h, wave * 16 + lrow, 128, 0, quad);
#pragma unroll
    for (int kc = 0; kc < 4; ++kc) {
      const int cur = kc & 1, nxt = cur ^ 1;
      if (kc < 3) bfp[nxt] = load_B(W2h, wave * 16 + lrow, 128, kc + 1, quad);
#pragma unroll
      for (int m = 0; m < 4; ++m) {
        f16x8 a = *(const f16x8*)(Xs + (m * 16 + lrow) * 138 + kc * 32 + quad * 8);
        acc[m] = __builtin_amdgcn_mfma_f32_16x16x32_f16(a, bfp[cur], acc[m], 0, 0, 0);
      }
    }
    int col = wave * 16 + lrow;
    float bv = b2[col];
#pragma unroll
    for (int m = 0; m < 4; ++m)
#pragma unroll
      for (int reg = 0; reg < 4; ++reg)
        X2s[(m * 16 + quad * 4 + reg) * 138 + col] = (_Float16)fmaxf(acc[m][reg] + bv, 0.f);
  }
  __syncthreads();

  // ---- Phase E: out (2 N-tiles/wave, 4 m) ----
  {
    f32x4 acc[4][2];
#pragma unroll
    for (int m = 0; m < 4; ++m) { acc[m][0] = (f32x4)0.0f; acc[m][1] = (f32x4)0.0f; }
    f16x8 bfp[2][2];
#pragma unroll
    for (int j = 0; j < 2; ++j)
      bfp[0][j] = load_B(W3h, wave * 32 + j * 16 + lrow, 128, 0, quad);
#pragma unroll
    for (int kc = 0; kc < 4; ++kc) {
      const int cur = kc & 1, nxt = cur ^ 1;
      if (kc < 3) {
#pragma unroll
        for (int j = 0; j < 2; ++j)
          bfp[nxt][j] = load_B(W3h, wave * 32 + j * 16 + lrow, 128, kc + 1, quad);
      }
#pragma unroll
      for (int m = 0; m < 4; ++m) {
        f16x8 a = *(const f16x8*)(X2s + (m * 16 + lrow) * 138 + kc * 32 + quad * 8);
#pragma unroll
        for (int j = 0; j < 2; ++j)
          acc[m][j] = __builtin_amdgcn_mfma_f32_16x16x32_f16(a, bfp[cur][j], acc[m][j], 0, 0, 0);
      }
    }
#pragma unroll
    for (int m = 0; m < 4; ++m) {
#pragma unroll
      for (int j = 0; j < 2; ++j) {
        int col = wave * 32 + j * 16 + lrow;
        float bv = b3[col];
#pragma unroll
        for (int reg = 0; reg < 4; ++reg) {
          int gm = r0 + m * 16 + quad * 4 + reg;
          if (gm < N_NODES)
            out[(size_t)gm * 256 + col] = acc[m][j][reg] + bv;
        }
      }
    }
  }
}

// ---------- launch: 4 dispatches ----------
extern "C" void kernel_launch(void* const* d_in, const int* in_sizes, int n_in,
                              void* d_out, int out_size, void* d_ws, size_t ws_size,
                              hipStream_t stream) {
  const float* feat  = (const float*)d_in[0];
  const int* src = (const int*)d_in[1];
  const int* dst = (const int*)d_in[2];
  const int* rel = (const int*)d_in[3];
  const float* W_rel = (const float*)d_in[4];
  const float* b_rel = (const float*)d_in[5];
  const float* W_ih  = (const float*)d_in[6];
  const float* b_ih  = (const float*)d_in[7];
  const float* b_hh  = (const float*)d_in[8];
  const float* W1 = (const float*)d_in[9];
  const float* b1 = (const float*)d_in[10];
  const float* W2 = (const float*)d_in[11];
  const float* b2 = (const float*)d_in[12];
  const float* W3 = (const float*)d_in[13];
  const float* b3 = (const float*)d_in[14];
  float* out = (float*)d_out;

  char* ws = (char*)d_ws;
  _Float16* Mh   = (_Float16*)(ws);              // 10,240,000 B (2 rel slabs)
  _Float16* aggh = (_Float16*)(ws + 10240000);   //  5,120,000
  char* wsb = ws + 15360000;
  _Float16* W_relh = (_Float16*)(wsb);             // 262,144
  _Float16* Wg     = (_Float16*)(wsb + 262144);    // 393,216
  _Float16* W1h    = (_Float16*)(wsb + 655360);    // 65,536
  _Float16* W2h    = (_Float16*)(wsb + 720896);    // 32,768
  _Float16* W3h    = (_Float16*)(wsb + 753664);    // 65,536
  float*    bg     = (float*)(wsb + 819200);       // 3,072
  int*      cnt    = (int*)(wsb + 822272);         // 40,000
  unsigned int* rowoff = (unsigned int*)(wsb + 862272);  // 5,120,000 (10000*128*4)

  // K0: cnt zero + all weight casts
  prep_cast<<<822, 512, 0, stream>>>(cnt, W_rel, W_ih, b_ih, b_hh, W1, W2, W3,
                                     W_relh, Wg, bg, W1h, W2h, W3h);
  // K1: edge NN GEMM (dbuf staged M=64) + bucket fill (overlapped)
  edge_fill<<<939, 512, 0, stream>>>(feat, W_relh, b_rel, Mh,
                                     dst, src, rel, cnt, rowoff);
  // K2: scatter-sum via LDS-staged bucket gather (wide TLP: one block per node)
  agg_kernel<<<N_NODES, 256, 0, stream>>>(cnt, rowoff, Mh, aggh);
  // K3: gates + LSTM + MLP -> out (M=64/block, ping-pong prefetch, direct B-loads)
  tail<<<157, 512, 0, stream>>>(aggh, Wg, bg, W1h, b1, W2h, b2, W3h, b3, out);
}

// Round 16
// 177.195 us; speedup vs baseline: 1.0051x; 1.0051x over previous
//
#include <hip/hip_runtime.h>
#include <hip/hip_bf16.h>

#define N_NODES 10000
#define N_EDGES 320000
#define D 256

typedef __attribute__((ext_vector_type(8))) _Float16 f16x8;
typedef __attribute__((ext_vector_type(4))) _Float16 f16x4;
typedef __attribute__((ext_vector_type(4))) float f32x4;

__device__ __forceinline__ void async_copy16(const void* g, void* l) {
  __builtin_amdgcn_global_load_lds(
      (const __attribute__((address_space(1))) unsigned int*)g,
      (__attribute__((address_space(3))) unsigned int*)l, 16, 0, 0);
}

// stage ROWS x 32 f16 k-chunk into Bs[ROWS*32] with XOR quad swizzle; WAVES waves cooperate
template<int ROWS, int WAVES>
__device__ __forceinline__ void stage_tile(const _Float16* __restrict__ Wb, int k0, int K,
                                           _Float16* Bs, int wave, int lane) {
  const int sr = lane >> 2, ss = lane & 3;
#pragma unroll
  for (int grp = wave; grp < ROWS / 16; grp += WAVES) {
    int r = grp * 16 + sr;
    int gq = ss ^ ((r >> 1) & 3);
    async_copy16(Wb + (size_t)r * K + k0 + gq * 8, Bs + grp * 512);
  }
}
__device__ __forceinline__ f16x8 read_B(const _Float16* Bs, int r, int quad) {
  return *(const f16x8*)(Bs + r * 32 + (quad ^ ((r >> 1) & 3)) * 8);
}

// direct B-fragment load: W row-major [N x K], fragment = 8 f16 at (row, kc*32 + quad*8)
__device__ __forceinline__ f16x8 load_B(const _Float16* __restrict__ W, int row, int K,
                                        int kc, int quad) {
  return *(const f16x8*)(W + (size_t)row * K + kc * 32 + quad * 8);
}

__device__ __forceinline__ float fast_sigmoid(float x) {
  return __builtin_amdgcn_rcpf(1.f + __expf(-x));
}
__device__ __forceinline__ float fast_tanh(float x) {
  float ax = fabsf(x);
  float e = __expf(-2.f * ax);
  float t = (1.f - e) * __builtin_amdgcn_rcpf(1.f + e);
  return copysignf(t, x);
}

// ---------- K0: cnt zeroing + all weight casts (absorbs memset) ----------
__global__ __launch_bounds__(512) void prep_cast(
    int* __restrict__ cnt,
    const float* __restrict__ W_rel, const float* __restrict__ W_ih,
    const float* __restrict__ b_ih, const float* __restrict__ b_hh,
    const float* __restrict__ W1, const float* __restrict__ W2,
    const float* __restrict__ W3,
    _Float16* __restrict__ W_relh, _Float16* __restrict__ Wg,
    float* __restrict__ bg,
    _Float16* __restrict__ W1h, _Float16* __restrict__ W2h,
    _Float16* __restrict__ W3h) {
  int i = blockIdx.x * 512 + threadIdx.x;
  if (i < 10240) { if (i < N_NODES) cnt[i] = 0; return; }
  i -= 10240;
  if (i < 131072) { W_relh[i] = (_Float16)W_rel[i]; return; }
  i -= 131072;
  if (i < 196608) {
    // packed row p = 48t + 16*phase + u -> W_ih row (16t+u) + {0,512,768}[phase] (f-gate dropped: c0=0)
    int p = i >> 8, k = i & 255;
    int t = p / 48, rem = p - t * 48;
    int phase = rem >> 4, u = rem & 15;
    int orig = t * 16 + u + (phase == 1 ? 512 : (phase == 2 ? 768 : 0));
    Wg[i] = (_Float16)W_ih[orig * 256 + k]; return;
  }
  i -= 196608;
  if (i < 32768) { W1h[i] = (_Float16)W1[i]; return; }
  i -= 32768;
  if (i < 16384) { W2h[i] = (_Float16)W2[i]; return; }
  i -= 16384;
  if (i < 32768) { W3h[i] = (_Float16)W3[i]; return; }
  i -= 32768;
  if (i < 768) {
    int t = i / 48, rem = i - t * 48;
    int phase = rem >> 4, u = rem & 15;
    int orig = t * 16 + u + (phase == 1 ? 512 : (phase == 2 ? 768 : 0));
    bg[i] = b_ih[orig] + b_hh[orig];
  }
}

// ---------- K1: fused edge NN (R2-proven: M=64, 8 waves, staged W) + bucket fill ----------
__global__ __launch_bounds__(512) void edge_fill(
    const float* __restrict__ feat, const _Float16* __restrict__ W_relh,
    const float* __restrict__ b_rel, _Float16* __restrict__ Mh,
    const int* __restrict__ dst, const int* __restrict__ src,
    const int* __restrict__ rel,
    int* __restrict__ cnt, unsigned int* __restrict__ rowoff)
{
  __shared__ _Float16 Hs[64 * 266];
  __shared__ alignas(16) _Float16 Bs[256 * 32];
  const int b = blockIdx.x;
  if (b >= 314) {
    // bucket-fill role: runs concurrently with the edge GEMM blocks
    int i = (b - 314) * 512 + threadIdx.x;   // 625*512 == N_EDGES exactly
    int v = dst[i];
    int pos = atomicAdd(&cnt[v], 1);
    if (pos < 128)   // capacity guard; P(deg>128) ~ 1e-40 for E/N=32
      rowoff[(v << 7) + pos] = (unsigned int)((rel[i] * N_NODES + src[i]) * D);
    return;
  }
  const int t = threadIdx.x;
  const int wave = t >> 6, lane = t & 63;
  const int quad = lane >> 4, lrow = lane & 15;
  const int z = (b >= 157) ? 1 : 0;
  const int m0 = (b - z * 157) * 64;
  const _Float16* Wb = W_relh + z * 65536;
  const float* bb = b_rel + z * 256;
  const int wm = (wave >> 2) * 32;
  const int wn = (wave & 3) * 64;

  int ar0 = m0 + wm + lrow;      if (ar0 > N_NODES - 1) ar0 = N_NODES - 1;
  int ar1 = m0 + wm + 16 + lrow; if (ar1 > N_NODES - 1) ar1 = N_NODES - 1;
  const float* fr0 = feat + (size_t)ar0 * 256;
  const float* fr1 = feat + (size_t)ar1 * 256;

  f32x4 acc[2][4];
#pragma unroll
  for (int i = 0; i < 2; ++i)
#pragma unroll
    for (int j = 0; j < 4; ++j) acc[i][j] = (f32x4)0.0f;

#pragma unroll
  for (int kc = 0; kc < 8; ++kc) {
    stage_tile<256, 8>(Wb, kc * 32, 256, Bs, wave, lane);
    float4 u0 = *(const float4*)(fr0 + kc * 32 + quad * 8);
    float4 u1 = *(const float4*)(fr0 + kc * 32 + quad * 8 + 4);
    float4 v0 = *(const float4*)(fr1 + kc * 32 + quad * 8);
    float4 v1 = *(const float4*)(fr1 + kc * 32 + quad * 8 + 4);
    f16x8 af0, af1;
    af0[0] = (_Float16)u0.x; af0[1] = (_Float16)u0.y; af0[2] = (_Float16)u0.z; af0[3] = (_Float16)u0.w;
    af0[4] = (_Float16)u1.x; af0[5] = (_Float16)u1.y; af0[6] = (_Float16)u1.z; af0[7] = (_Float16)u1.w;
    af1[0] = (_Float16)v0.x; af1[1] = (_Float16)v0.y; af1[2] = (_Float16)v0.z; af1[3] = (_Float16)v0.w;
    af1[4] = (_Float16)v1.x; af1[5] = (_Float16)v1.y; af1[6] = (_Float16)v1.z; af1[7] = (_Float16)v1.w;
    __syncthreads();
#pragma unroll
    for (int j = 0; j < 4; ++j) {
      f16x8 bf = read_B(Bs, wn + j * 16 + lrow, quad);
      acc[0][j] = __builtin_amdgcn_mfma_f32_16x16x32_f16(af0, bf, acc[0][j], 0, 0, 0);
      acc[1][j] = __builtin_amdgcn_mfma_f32_16x16x32_f16(af1, bf, acc[1][j], 0, 0, 0);
    }
    __syncthreads();
  }
#pragma unroll
  for (int i = 0; i < 2; ++i) {
    int rb = wm + i * 16 + quad * 4;
#pragma unroll
    for (int j = 0; j < 4; ++j) {
      int col = wn + j * 16 + lrow;
      float bv = bb[col];
#pragma unroll
      for (int reg = 0; reg < 4; ++reg) {
        Hs[(rb + reg) * 266 + col] = (_Float16)fmaxf(acc[i][j][reg] + bv, 0.f);
        acc[i][j][reg] = 0.f;
      }
    }
  }
  __syncthreads();

#pragma unroll
  for (int kc = 0; kc < 8; ++kc) {
    stage_tile<256, 8>(Wb, kc * 32, 256, Bs, wave, lane);
    f16x8 af0 = *(const f16x8*)(Hs + (wm + lrow) * 266 + kc * 32 + quad * 8);
    f16x8 af1 = *(const f16x8*)(Hs + (wm + 16 + lrow) * 266 + kc * 32 + quad * 8);
    __syncthreads();
#pragma unroll
    for (int j = 0; j < 4; ++j) {
      f16x8 bf = read_B(Bs, wn + j * 16 + lrow, quad);
      acc[0][j] = __builtin_amdgcn_mfma_f32_16x16x32_f16(af0, bf, acc[0][j], 0, 0, 0);
      acc[1][j] = __builtin_amdgcn_mfma_f32_16x16x32_f16(af1, bf, acc[1][j], 0, 0, 0);
    }
    __syncthreads();
  }
  _Float16* Mo = Mh + (size_t)z * (N_NODES * D);
#pragma unroll
  for (int i = 0; i < 2; ++i) {
    int rb = m0 + wm + i * 16 + quad * 4;
#pragma unroll
    for (int j = 0; j < 4; ++j) {
      int col = wn + j * 16 + lrow;
      float bv = bb[col];
#pragma unroll
      for (int reg = 0; reg < 4; ++reg) {
        int gm = rb + reg;
        if (gm < N_NODES)
          Mo[(size_t)gm * D + col] = (_Float16)fmaxf(acc[i][j][reg] + bv, 0.f);
      }
    }
  }
}

// ---------- K2: aggregation v3 (R13-proven): offsets staged to LDS, f16x8 loads, unroll-2 ----------
__global__ __launch_bounds__(256) void agg_kernel(const int* __restrict__ cnt,
                                                  const unsigned int* __restrict__ rowoff,
                                                  const _Float16* __restrict__ Mh,
                                                  _Float16* __restrict__ aggh) {
  __shared__ unsigned int soff[128];
  __shared__ float part[4][256];
  const int node = blockIdx.x;
  const int tid = threadIdx.x;
  const int wave = tid >> 6, lane = tid & 63;
  const int half = lane >> 5, li = lane & 31;
  const int base = node << 7;
  if (tid < 128) soff[tid] = rowoff[base + tid];
  int deg = cnt[node]; if (deg > 128) deg = 128;
  __syncthreads();

  float a0 = 0.f, a1 = 0.f, a2 = 0.f, a3 = 0.f, a4 = 0.f, a5 = 0.f, a6 = 0.f, a7 = 0.f;
  // lane handles channels li*8..li*8+7 of rows j = wave*2 + half (+8k); offsets from LDS
  int j = wave * 2 + half;
  for (; j + 8 < deg; j += 16) {   // unroll-2: two row loads in flight
    unsigned int offA = soff[j];
    unsigned int offB = soff[j + 8];
    f16x8 vA = *(const f16x8*)(Mh + (size_t)offA + li * 8);
    f16x8 vB = *(const f16x8*)(Mh + (size_t)offB + li * 8);
    a0 += (float)vA[0] + (float)vB[0]; a1 += (float)vA[1] + (float)vB[1];
    a2 += (float)vA[2] + (float)vB[2]; a3 += (float)vA[3] + (float)vB[3];
    a4 += (float)vA[4] + (float)vB[4]; a5 += (float)vA[5] + (float)vB[5];
    a6 += (float)vA[6] + (float)vB[6]; a7 += (float)vA[7] + (float)vB[7];
  }
  for (; j < deg; j += 8) {
    unsigned int off = soff[j];
    f16x8 v = *(const f16x8*)(Mh + (size_t)off + li * 8);
    a0 += (float)v[0]; a1 += (float)v[1]; a2 += (float)v[2]; a3 += (float)v[3];
    a4 += (float)v[4]; a5 += (float)v[5]; a6 += (float)v[6]; a7 += (float)v[7];
  }
  // combine the two 32-lane halves — all lanes reconverged here, shfl is safe
  a0 += __shfl_xor(a0, 32); a1 += __shfl_xor(a1, 32);
  a2 += __shfl_xor(a2, 32); a3 += __shfl_xor(a3, 32);
  a4 += __shfl_xor(a4, 32); a5 += __shfl_xor(a5, 32);
  a6 += __shfl_xor(a6, 32); a7 += __shfl_xor(a7, 32);
  if (lane < 32) {   // lanes 0..31 store the wave partial (32..63 duplicate)
    *(float4*)&part[wave][li * 8]     = make_float4(a0, a1, a2, a3);
    *(float4*)&part[wave][li * 8 + 4] = make_float4(a4, a5, a6, a7);
  }
  __syncthreads();
  if (wave == 0) {
    float4 p0 = *(const float4*)&part[0][lane * 4];
    float4 p1 = *(const float4*)&part[1][lane * 4];
    float4 p2 = *(const float4*)&part[2][lane * 4];
    float4 p3 = *(const float4*)&part[3][lane * 4];
    f16x4 o;
    o[0] = (_Float16)(p0.x + p1.x + p2.x + p3.x);
    o[1] = (_Float16)(p0.y + p1.y + p2.y + p3.y);
    o[2] = (_Float16)(p0.z + p1.z + p2.z + p3.z);
    o[3] = (_Float16)(p0.w + p1.w + p2.w + p3.w);
    *(f16x4*)(aggh + (size_t)node * D + lane * 4) = o;
  }
}

// ---------- K3: tail (R8-proven), M=64/block, ping-pong prefetch, direct B-loads ----------
__global__ __launch_bounds__(512) void tail(
    const _Float16* __restrict__ aggh,
    const _Float16* __restrict__ Wg, const float* __restrict__ bg,
    const _Float16* __restrict__ W1h, const float* __restrict__ b1,
    const _Float16* __restrict__ W2h, const float* __restrict__ b2,
    const _Float16* __restrict__ W3h, const float* __restrict__ b3,
    float* __restrict__ out)
{
  __shared__ _Float16 Hn[64 * 266];    // 34,048 B
  __shared__ _Float16 Xs[64 * 138];    // 17,664 B
  __shared__ _Float16 X2s[64 * 138];   // 17,664 B
  const int t = threadIdx.x;
  const int wave = t >> 6, lane = t & 63;
  const int quad = lane >> 4, lrow = lane & 15;
  const int r0 = blockIdx.x * 64;   // 157 * 64 = 10048 >= N_NODES (guarded)

  int ar[4];
#pragma unroll
  for (int m = 0; m < 4; ++m) {
    int a = r0 + m * 16 + lrow;
    ar[m] = (a > N_NODES - 1) ? (N_NODES - 1) : a;
  }

  // ---- Phase B: gates + LSTM -> Hn (8 waves x 6 gate-tiles x 4 m-subtiles) ----
  {
    f32x4 acc[4][6];
#pragma unroll
    for (int m = 0; m < 4; ++m)
#pragma unroll
      for (int j = 0; j < 6; ++j) acc[m][j] = (f32x4)0.0f;

    f16x8 afp[2][4], bfp[2][6];
#pragma unroll
    for (int m = 0; m < 4; ++m)
      afp[0][m] = *(const f16x8*)(aggh + (size_t)ar[m] * 256 + quad * 8);
#pragma unroll
    for (int j = 0; j < 6; ++j)
      bfp[0][j] = load_B(Wg, (wave * 6 + j) * 16 + lrow, 256, 0, quad);

#pragma unroll
    for (int kc = 0; kc < 8; ++kc) {
      const int cur = kc & 1, nxt = cur ^ 1;
      if (kc < 7) {   // prefetch kc+1 while MFMAs below run on kc
#pragma unroll
        for (int m = 0; m < 4; ++m)
          afp[nxt][m] = *(const f16x8*)(aggh + (size_t)ar[m] * 256 + (kc + 1) * 32 + quad * 8);
#pragma unroll
        for (int j = 0; j < 6; ++j)
          bfp[nxt][j] = load_B(Wg, (wave * 6 + j) * 16 + lrow, 256, kc + 1, quad);
      }
#pragma unroll
      for (int j = 0; j < 6; ++j)
#pragma unroll
        for (int m = 0; m < 4; ++m)
          acc[m][j] = __builtin_amdgcn_mfma_f32_16x16x32_f16(afp[cur][m], bfp[cur][j], acc[m][j], 0, 0, 0);
    }
#pragma unroll
    for (int m = 0; m < 4; ++m) {
#pragma unroll
      for (int p = 0; p < 2; ++p) {
        float bvi = bg[(wave * 6 + 3 * p + 0) * 16 + lrow];
        float bvg = bg[(wave * 6 + 3 * p + 1) * 16 + lrow];
        float bvo = bg[(wave * 6 + 3 * p + 2) * 16 + lrow];
        int dcol = (wave * 2 + p) * 16 + lrow;
#pragma unroll
        for (int reg = 0; reg < 4; ++reg) {
          float vi = acc[m][3 * p + 0][reg] + bvi;
          float vg = acc[m][3 * p + 1][reg] + bvg;
          float vo = acc[m][3 * p + 2][reg] + bvo;
          float c = fast_sigmoid(vi) * fast_tanh(vg);
          Hn[(m * 16 + quad * 4 + reg) * 266 + dcol] = (_Float16)(fast_sigmoid(vo) * fast_tanh(c));
        }
      }
    }
  }
  __syncthreads();

  // ---- Phase C: x1 (1 N-tile/wave, 4 m; A from LDS, B prefetched) ----
  {
    f32x4 acc[4];
#pragma unroll
    for (int m = 0; m < 4; ++m) acc[m] = (f32x4)0.0f;
    f16x8 bfp[2];
    bfp[0] = load_B(W1h, wave * 16 + lrow, 256, 0, quad);
#pragma unroll
    for (int kc = 0; kc < 8; ++kc) {
      const int cur = kc & 1, nxt = cur ^ 1;
      if (kc < 7) bfp[nxt] = load_B(W1h, wave * 16 + lrow, 256, kc + 1, quad);
#pragma unroll
      for (int m = 0; m < 4; ++m) {
        f16x8 a = *(const f16x8*)(Hn + (m * 16 + lrow) * 266 + kc * 32 + quad * 8);
        acc[m] = __builtin_amdgcn_mfma_f32_16x16x32_f16(a, bfp[cur], acc[m], 0, 0, 0);
      }
    }
    int col = wave * 16 + lrow;
    float bv = b1[col];
#pragma unroll
    for (int m = 0; m < 4; ++m)
#pragma unroll
      for (int reg = 0; reg < 4; ++reg)
        Xs[(m * 16 + quad * 4 + reg) * 138 + col] = (_Float16)fmaxf(acc[m][reg] + bv, 0.f);
  }
  __syncthreads();

  // ---- Phase D: x2 (1 N-tile/wave, 4 m) ----
  {
    f32x4 acc[4];
#pragma unroll
    for (int m = 0; m < 4; ++m) acc[m] = (f32x4)0.0f;
    f16x8 bfp[2];
    bfp[0] = load_B(W2h, wave * 16 + lrow, 128, 0, quad);
#pragma unroll
    for (int kc = 0; kc < 4; ++kc) {
      const int cur = kc & 1, nxt = cur ^ 1;
      if (kc < 3) bfp[nxt] = load_B(W2h, wave * 16 + lrow, 128, kc + 1, quad);
#pragma unroll
      for (int m = 0; m < 4; ++m) {
        f16x8 a = *(const f16x8*)(Xs + (m * 16 + lrow) * 138 + kc * 32 + quad * 8);
        acc[m] = __builtin_amdgcn_mfma_f32_16x16x32_f16(a, bfp[cur], acc[m], 0, 0, 0);
      }
    }
    int col = wave * 16 + lrow;
    float bv = b2[col];
#pragma unroll
    for (int m = 0; m < 4; ++m)
#pragma unroll
      for (int reg = 0; reg < 4; ++reg)
        X2s[(m * 16 + quad * 4 + reg) * 138 + col] = (_Float16)fmaxf(acc[m][reg] + bv, 0.f);
  }
  __syncthreads();

  // ---- Phase E: out (2 N-tiles/wave, 4 m) ----
  {
    f32x4 acc[4][2];
#pragma unroll
    for (int m = 0; m < 4; ++m) { acc[m][0] = (f32x4)0.0f; acc[m][1] = (f32x4)0.0f; }
    f16x8 bfp[2][2];
#pragma unroll
    for (int j = 0; j < 2; ++j)
      bfp[0][j] = load_B(W3h, wave * 32 + j * 16 + lrow, 128, 0, quad);
#pragma unroll
    for (int kc = 0; kc < 4; ++kc) {
      const int cur = kc & 1, nxt = cur ^ 1;
      if (kc < 3) {
#pragma unroll
        for (int j = 0; j < 2; ++j)
          bfp[nxt][j] = load_B(W3h, wave * 32 + j * 16 + lrow, 128, kc + 1, quad);
      }
#pragma unroll
      for (int m = 0; m < 4; ++m) {
        f16x8 a = *(const f16x8*)(X2s + (m * 16 + lrow) * 138 + kc * 32 + quad * 8);
#pragma unroll
        for (int j = 0; j < 2; ++j)
          acc[m][j] = __builtin_amdgcn_mfma_f32_16x16x32_f16(a, bfp[cur][j], acc[m][j], 0, 0, 0);
      }
    }
#pragma unroll
    for (int m = 0; m < 4; ++m) {
#pragma unroll
      for (int j = 0; j < 2; ++j) {
        int col = wave * 32 + j * 16 + lrow;
        float bv = b3[col];
#pragma unroll
        for (int reg = 0; reg < 4; ++reg) {
          int gm = r0 + m * 16 + quad * 4 + reg;
          if (gm < N_NODES)
            out[(size_t)gm * 256 + col] = acc[m][j][reg] + bv;
        }
      }
    }
  }
}

// ---------- launch: 4 dispatches ----------
extern "C" void kernel_launch(void* const* d_in, const int* in_sizes, int n_in,
                              void* d_out, int out_size, void* d_ws, size_t ws_size,
                              hipStream_t stream) {
  const float* feat  = (const float*)d_in[0];
  const int* src = (const int*)d_in[1];
  const int* dst = (const int*)d_in[2];
  const int* rel = (const int*)d_in[3];
  const float* W_rel = (const float*)d_in[4];
  const float* b_rel = (const float*)d_in[5];
  const float* W_ih  = (const float*)d_in[6];
  const float* b_ih  = (const float*)d_in[7];
  const float* b_hh  = (const float*)d_in[8];
  const float* W1 = (const float*)d_in[9];
  const float* b1 = (const float*)d_in[10];
  const float* W2 = (const float*)d_in[11];
  const float* b2 = (const float*)d_in[12];
  const float* W3 = (const float*)d_in[13];
  const float* b3 = (const float*)d_in[14];
  float* out = (float*)d_out;

  char* ws = (char*)d_ws;
  _Float16* Mh   = (_Float16*)(ws);              // 10,240,000 B (2 rel slabs)
  _Float16* aggh = (_Float16*)(ws + 10240000);   //  5,120,000
  char* wsb = ws + 15360000;
  _Float16* W_relh = (_Float16*)(wsb);             // 262,144
  _Float16* Wg     = (_Float16*)(wsb + 262144);    // 393,216
  _Float16* W1h    = (_Float16*)(wsb + 655360);    // 65,536
  _Float16* W2h    = (_Float16*)(wsb + 720896);    // 32,768
  _Float16* W3h    = (_Float16*)(wsb + 753664);    // 65,536
  float*    bg     = (float*)(wsb + 819200);       // 3,072
  int*      cnt    = (int*)(wsb + 822272);         // 40,000
  unsigned int* rowoff = (unsigned int*)(wsb + 862272);  // 5,120,000 (10000*128*4)

  // K0: cnt zero + all weight casts
  prep_cast<<<822, 512, 0, stream>>>(cnt, W_rel, W_ih, b_ih, b_hh, W1, W2, W3,
                                     W_relh, Wg, bg, W1h, W2h, W3h);
  // K1: edge NN GEMM (R2-proven M=64 staged) + bucket fill (overlapped)
  edge_fill<<<939, 512, 0, stream>>>(feat, W_relh, b_rel, Mh,
                                     dst, src, rel, cnt, rowoff);
  // K2: scatter-sum via LDS-staged bucket gather (wide TLP: one block per node)
  agg_kernel<<<N_NODES, 256, 0, stream>>>(cnt, rowoff, Mh, aggh);
  // K3: gates + LSTM + MLP -> out (M=64/block, ping-pong prefetch, direct B-loads)
  tail<<<157, 512, 0, stream>>>(aggh, Wg, bg, W1h, b1, W2h, b2, W3h, b3, out);
}